// Round 5
// baseline (130.527 us; speedup 1.0000x reference)
//
#include <hip/hip_runtime.h>
#include <hip/hip_bf16.h>

// ---------- types ----------
typedef __attribute__((ext_vector_type(8))) short bf16x8;   // 8 bf16 in 4 VGPRs
typedef __attribute__((ext_vector_type(4))) short bf16x4;   // 4 bf16 in 2 VGPRs
typedef __attribute__((ext_vector_type(4))) float f32x4;
typedef __attribute__((ext_vector_type(4))) int   i32x4;

#define C2LOG 0.18033688011112042f   // 0.125 * log2(e): folds 1/sqrt(64) + base-2

// fp32 -> bf16 round-to-nearest-even
__device__ __forceinline__ short f2bf(float f) {
    union { float f; unsigned u; } v; v.f = f;
    unsigned r = v.u + 0x7fff + ((v.u >> 16) & 1);
    return (short)(r >> 16);
}
__device__ __forceinline__ unsigned packbf(float a, float b) {
    return (unsigned)(unsigned short)f2bf(a) | ((unsigned)(unsigned short)f2bf(b) << 16);
}
__device__ __forceinline__ float bf2f(short s) {
    union { unsigned u; float f; } v; v.u = ((unsigned)(unsigned short)s) << 16;
    return v.f;
}

// ---------- sizes ----------
#define BB 4
#define TT 4096
#define CC 1024
#define HD 64
#define NTASK_PB 144          // tasks per batch: sum_{g=0}^{7} 4*(g+1) = 144
#define NTASK (BB * NTASK_PB) // 576

// =====================================================================
// Kernel 1: pack W q/k/v (fp32 [1024][64]) -> transposed bf16 Wt[192][1024]
// =====================================================================
__global__ void prep_w(const float* __restrict__ Wq, const float* __restrict__ Wk,
                       const float* __restrict__ Wv, short* __restrict__ Wt) {
    const int n = blockIdx.x;                 // 0..191
    const float* W = (n < 64) ? Wq : (n < 128) ? Wk : Wv;
    const int col = n & 63;
    for (int k = threadIdx.x; k < CC; k += blockDim.x)
        Wt[n * CC + k] = f2bf(W[k * HD + col]);
}

// =====================================================================
// Kernel 2: QKV projection, x-stationary. Block = 32 rows of x.
// Stage full-K x tile (bf16, XOR-swizzled) once -> ONE barrier.
// W (L2-resident) streamed directly from global in the K-loop.
// Wave wv: m-half (wv&1), n-chunks (wv>>1)*3..+3.
// =====================================================================
__global__ __launch_bounds__(512) void proj_qkv(const float* __restrict__ x,
        const short* __restrict__ Wt, short* __restrict__ Q,
        short* __restrict__ K, short* __restrict__ Vt) {
    __shared__ short xs[32 * 1024];    // 64 KB, swizzled: byte ^= (row&7)<<4

    const int tid  = threadIdx.x;
    const int lane = tid & 63;
    const int wv   = tid >> 6;
    const int lm   = lane & 15;
    const int lg   = lane >> 4;
    const int mhalf = wv & 1;
    const int ngrp  = wv >> 1;
    const int mbase = blockIdx.x * 32;

    // ---- stage x [32 rows][1024 k] fp32 -> bf16, swizzled ----
    {
        const int r  = tid >> 4;               // 0..31
        const int cb = (tid & 15) << 3;        // 0..120 step 8
        const float* xrow = x + (size_t)(mbase + r) * CC;
        char* drow = (char*)xs + r * 2048;
        const int sw = (r & 7) << 4;
        #pragma unroll
        for (int j = 0; j < 8; ++j) {
            const int col = j * 128 + cb;      // 16 lanes -> 512B contiguous
            float4 v0 = *reinterpret_cast<const float4*>(xrow + col);
            float4 v1 = *reinterpret_cast<const float4*>(xrow + col + 4);
            bf16x8 bvec;
            bvec[0] = f2bf(v0.x); bvec[1] = f2bf(v0.y);
            bvec[2] = f2bf(v0.z); bvec[3] = f2bf(v0.w);
            bvec[4] = f2bf(v1.x); bvec[5] = f2bf(v1.y);
            bvec[6] = f2bf(v1.z); bvec[7] = f2bf(v1.w);
            *reinterpret_cast<bf16x8*>(drow + ((col * 2) ^ sw)) = bvec;
        }
    }
    __syncthreads();

    // ---- K-loop: A from LDS, B direct from global (L2), no barriers ----
    const int arow = mhalf * 16 + lm;
    const char* abase = (const char*)xs + arow * 2048;
    const int asw = (arow & 7) << 4;

    f32x4 acc[3];
    #pragma unroll
    for (int i = 0; i < 3; ++i) acc[i] = f32x4{0.f, 0.f, 0.f, 0.f};

    #pragma unroll 4
    for (int k0 = 0; k0 < CC; k0 += 32) {
        bf16x8 a = *reinterpret_cast<const bf16x8*>(
            abase + (((k0 * 2) + lg * 16) ^ asw));
        #pragma unroll
        for (int c = 0; c < 3; ++c) {
            const int cn = ngrp * 3 + c;
            bf16x8 bfr = *reinterpret_cast<const bf16x8*>(
                Wt + (size_t)(cn * 16 + lm) * CC + k0 + lg * 8);
            acc[c] = __builtin_amdgcn_mfma_f32_16x16x32_bf16(a, bfr, acc[c], 0, 0, 0);
        }
    }

    // ---- store: D row = mhalf*16 + lg*4 + r, col = cn*16 + lm ----
    const int mrow = mbase + mhalf * 16 + lg * 4;
    #pragma unroll
    for (int c = 0; c < 3; ++c) {
        const int cn = ngrp * 3 + c;
        if (cn < 4) {
            #pragma unroll
            for (int r = 0; r < 4; ++r)
                Q[(size_t)(mrow + r) * HD + cn * 16 + lm] = f2bf(acc[c][r]);
        } else if (cn < 8) {
            #pragma unroll
            for (int r = 0; r < 4; ++r)
                K[(size_t)(mrow + r) * HD + (cn - 4) * 16 + lm] = f2bf(acc[c][r]);
        } else {
            const int bb   = mbase >> 12;
            const int tloc = (mbase & 4095) + mhalf * 16 + lg * 4;
            bf16x4 v4;
            #pragma unroll
            for (int r = 0; r < 4; ++r) v4[r] = f2bf(acc[c][r]);
            *reinterpret_cast<bf16x4*>(
                Vt + (size_t)bb * (HD * TT) + (size_t)((cn - 8) * 16 + lm) * TT + tloc) = v4;
        }
    }
}

// =====================================================================
// Kernel 3: causal flash attention (unchanged from R4). Block = 128 q-rows
// (8 waves x 16), one KV segment; KV-64 tiles double-buffered in LDS via
// global_load_lds with XOR swizzle, shared by all 8 waves.
// =====================================================================
__global__ __launch_bounds__(512, 4) void attn(const short* __restrict__ Q,
        const short* __restrict__ K, const short* __restrict__ Vt,
        short* __restrict__ Opart, float* __restrict__ Mpart,
        float* __restrict__ Lpart) {
    __shared__ short ks[2][64 * 64];   // [buf][row=kv][d]  8KB each, swizzled
    __shared__ short vs[2][64 * 64];   // [buf][row=d][kv]  8KB each, swizzled

    const int tid  = threadIdx.x;
    const int lane = tid & 63;
    const int wv   = tid >> 6;
    const int lm   = lane & 15;
    const int lg   = lane >> 4;

    // ---- task decode: blockIdx.x = b*144 + t ----
    const int task = blockIdx.x;
    const int b  = task / NTASK_PB;
    int t_in = task - b * NTASK_PB;
    int g = 0;
    while (t_in >= 2 * (g + 1) * (g + 2)) ++g;          // g = i>>2, <=7
    const int idx = t_in - 2 * g * (g + 1);
    const int i   = 4 * g + idx / (g + 1);              // q-block 0..31
    const int seg = idx % (g + 1);                      // segment 0..g
    const int S   = g + 1;                              // segments for this i
    const int niter = 2 * i + 2;                        // KV-64 tiles in prefix
    const int qbase = i * 128;

    const size_t qkb = (size_t)b * TT * HD;
    const size_t vtb = (size_t)b * HD * TT;
    const int qrow = qbase + wv * 16;                   // wave's first q-row
    const int tmax = (qrow + 15) >> 6;                  // last useful tile

    // Q fragments (B-operand): lane holds Q[qrow+lm][lg*8+j]
    bf16x8 qf0 = *reinterpret_cast<const bf16x8*>(Q + qkb + (size_t)(qrow + lm) * HD + lg * 8);
    bf16x8 qf1 = *reinterpret_cast<const bf16x8*>(Q + qkb + (size_t)(qrow + lm) * HD + 32 + lg * 8);

    f32x4 o[4];
    #pragma unroll
    for (int c = 0; c < 4; ++c) o[c] = f32x4{0.f, 0.f, 0.f, 0.f};
    float mrun = -1e30f, lrun = 0.f;   // per-lane (q=lm), log2 domain

    const int srcA = lm + ((lane & 16) << 1);
    const int srcB = srcA + 16;
    const bool hihalf = (lane & 32) != 0;

    // staging geometry (per wave: 1KB chunk of each 8KB tile)
    const int lds_off = (wv << 10) + (lane << 4);       // byte offset in tile
    const int srow    = lds_off >> 7;                   // row this lane fills
    const int scolb   = (lds_off & 127) ^ ((srow & 7) << 4);  // pre-swizzled src col

#define STAGE_KV(bufidx, tt)                                                          \
    {                                                                                 \
        const char* ksrc = (const char*)(K + qkb) + (tt) * 8192 + (srow << 7) + scolb;\
        char* kdst = (char*)&ks[bufidx][0] + (wv << 10);                              \
        __builtin_amdgcn_global_load_lds(                                             \
            (const __attribute__((address_space(1))) unsigned*)ksrc,                  \
            (__attribute__((address_space(3))) unsigned*)kdst, 16, 0, 0);             \
        const char* vsrc = (const char*)(Vt + vtb) + (size_t)srow * (TT * 2)          \
                           + (tt) * 128 + scolb;                                      \
        char* vdst = (char*)&vs[bufidx][0] + (wv << 10);                              \
        __builtin_amdgcn_global_load_lds(                                             \
            (const __attribute__((address_space(1))) unsigned*)vsrc,                  \
            (__attribute__((address_space(3))) unsigned*)vdst, 16, 0, 0);             \
    }

    // prologue: stage first tile
    STAGE_KV(0, seg)
    asm volatile("s_waitcnt vmcnt(0)" ::: "memory");
    __syncthreads();

    int buf = 0;
    for (int t = seg; t < niter; t += S) {
        const int tn = t + S;
        if (tn < niter) STAGE_KV(buf ^ 1, tn)

        if (t <= tmax) {
            const short* ksb = &ks[buf][0];
            const short* vsb = &vs[buf][0];
            const int kv = t * 64;

            // ---- QK^T swapped: st[kt][r] = S[qrow+lm][kv + kt*16 + lg*4 + r] ----
            f32x4 st[4];
            #pragma unroll
            for (int kt = 0; kt < 4; ++kt) {
                const int krow = kt * 16 + lm;
                const int sw = (krow & 7) << 4;
                bf16x8 k0 = *reinterpret_cast<const bf16x8*>(
                    (const char*)ksb + krow * 128 + ((lg * 16) ^ sw));
                bf16x8 k1 = *reinterpret_cast<const bf16x8*>(
                    (const char*)ksb + krow * 128 + ((64 + lg * 16) ^ sw));
                f32x4 a = f32x4{0.f, 0.f, 0.f, 0.f};
                a = __builtin_amdgcn_mfma_f32_16x16x32_bf16(k0, qf0, a, 0, 0, 0);
                a = __builtin_amdgcn_mfma_f32_16x16x32_bf16(k1, qf1, a, 0, 0, 0);
                st[kt] = a;
            }
            // ---- to log2 domain + causal mask ----
            float s2[4][4];
            #pragma unroll
            for (int kt = 0; kt < 4; ++kt)
                #pragma unroll
                for (int r = 0; r < 4; ++r) s2[kt][r] = st[kt][r] * C2LOG;
            if (kv + 63 > qrow) {
                const int qg = qrow + lm;
                #pragma unroll
                for (int kt = 0; kt < 4; ++kt)
                    #pragma unroll
                    for (int r = 0; r < 4; ++r)
                        if (kv + kt * 16 + lg * 4 + r > qg) s2[kt][r] = -1e30f;
            }
            // ---- online softmax (q lane-local; 2 shfl per reduce) ----
            float mloc = s2[0][0];
            #pragma unroll
            for (int kt = 0; kt < 4; ++kt)
                #pragma unroll
                for (int r = 0; r < 4; ++r) mloc = fmaxf(mloc, s2[kt][r]);
            mloc = fmaxf(mloc, __shfl_xor(mloc, 16));
            mloc = fmaxf(mloc, __shfl_xor(mloc, 32));
            const float mnew = fmaxf(mrun, mloc);
            const float alpha = __builtin_amdgcn_exp2f(mrun - mnew);
            mrun = mnew;

            float p[4][4];
            float rs = 0.f;
            #pragma unroll
            for (int kt = 0; kt < 4; ++kt)
                #pragma unroll
                for (int r = 0; r < 4; ++r) {
                    p[kt][r] = __builtin_amdgcn_exp2f(s2[kt][r] - mnew);
                    rs += p[kt][r];
                }
            rs += __shfl_xor(rs, 16);
            rs += __shfl_xor(rs, 32);
            lrun = lrun * alpha + rs;

            // ---- pack P^T to bf16 pairs ----
            unsigned u[4][2];
            #pragma unroll
            for (int kt = 0; kt < 4; ++kt) {
                u[kt][0] = packbf(p[kt][0], p[kt][1]);
                u[kt][1] = packbf(p[kt][2], p[kt][3]);
            }
            // ---- rescale O^T ----
            #pragma unroll
            for (int c = 0; c < 4; ++c)
                #pragma unroll
                for (int r = 0; r < 4; ++r) o[c][r] *= alpha;

            // ---- PV: O^T += V^T . P ; B-frag via register redistribution ----
            #pragma unroll
            for (int h = 0; h < 2; ++h) {
                const int b0 = __shfl((int)u[2 * h][0], srcA);
                const int c0 = __shfl((int)u[2 * h + 1][0], srcA);
                const int b1 = __shfl((int)u[2 * h][1], srcA);
                const int c1 = __shfl((int)u[2 * h + 1][1], srcA);
                const int b2 = __shfl((int)u[2 * h][0], srcB);
                const int c2 = __shfl((int)u[2 * h + 1][0], srcB);
                const int b3 = __shfl((int)u[2 * h][1], srcB);
                const int c3 = __shfl((int)u[2 * h + 1][1], srcB);
                union { i32x4 iv; bf16x8 v; } cv;
                cv.iv = i32x4{ hihalf ? c0 : b0, hihalf ? c1 : b1,
                               hihalf ? c2 : b2, hihalf ? c3 : b3 };
                #pragma unroll
                for (int c = 0; c < 4; ++c) {
                    const int vrow = c * 16 + lm;
                    const int sw = (vrow & 7) << 4;
                    bf16x8 va = *reinterpret_cast<const bf16x8*>(
                        (const char*)vsb + vrow * 128 + ((h * 64 + lg * 16) ^ sw));
                    o[c] = __builtin_amdgcn_mfma_f32_16x16x32_bf16(va, cv.v, o[c], 0, 0, 0);
                }
            }
        }

        asm volatile("s_waitcnt vmcnt(0)" ::: "memory");
        __syncthreads();
        buf ^= 1;
    }
#undef STAGE_KV

    // ---- write partials: O bf16 (task,row,d), m/l fp32 ----
    short* Ob = Opart + (size_t)task * (128 * HD);
    #pragma unroll
    for (int c = 0; c < 4; ++c) {
        bf16x4 ov;
        #pragma unroll
        for (int r = 0; r < 4; ++r) ov[r] = f2bf(o[c][r]);
        *reinterpret_cast<bf16x4*>(&Ob[(wv * 16 + lm) * HD + c * 16 + lg * 4]) = ov;
    }
    if (lg == 0) {
        Mpart[task * 128 + wv * 16 + lm] = mrun;
        Lpart[task * 128 + wv * 16 + lm] = lrun;
    }
}

// =====================================================================
// Kernel 4: combine partials -> fp32 out. Block = one (b, q-block i).
// =====================================================================
__global__ __launch_bounds__(256) void combine(const short* __restrict__ Opart,
        const float* __restrict__ Mpart, const float* __restrict__ Lpart,
        float* __restrict__ out) {
    const int b = blockIdx.x >> 5;
    const int i = blockIdx.x & 31;
    const int g = i >> 2;
    const int S = g + 1;
    const int task0 = b * NTASK_PB + 2 * g * (g + 1) + (i - 4 * g) * (g + 1);
    const int qbase = i * 128;

    const int tid = threadIdx.x;
    const int r0  = tid >> 4;           // 0..15
    const int cb  = (tid & 15) << 2;    // col (x4 floats)

    for (int rr = 0; rr < 8; ++rr) {
        const int row = rr * 16 + r0;   // 0..127
        float mmax = -1e30f;
        float ms[8];
        for (int s = 0; s < S; ++s) {
            ms[s] = Mpart[(task0 + s) * 128 + row];
            mmax = fmaxf(mmax, ms[s]);
        }
        float lsum = 0.f;
        float a0 = 0.f, a1 = 0.f, a2 = 0.f, a3 = 0.f;
        for (int s = 0; s < S; ++s) {
            const float w = __builtin_amdgcn_exp2f(ms[s] - mmax);
            lsum += Lpart[(task0 + s) * 128 + row] * w;
            bf16x4 ov = *reinterpret_cast<const bf16x4*>(
                &Opart[((size_t)(task0 + s) * 128 + row) * HD + cb]);
            a0 += bf2f(ov[0]) * w;
            a1 += bf2f(ov[1]) * w;
            a2 += bf2f(ov[2]) * w;
            a3 += bf2f(ov[3]) * w;
        }
        const float inv = 1.0f / lsum;
        f32x4 res{ a0 * inv, a1 * inv, a2 * inv, a3 * inv };
        *reinterpret_cast<f32x4*>(
            &out[((size_t)b * TT + qbase + row) * HD + cb]) = res;
    }
}

// =====================================================================
extern "C" void kernel_launch(void* const* d_in, const int* in_sizes, int n_in,
                              void* d_out, int out_size, void* d_ws, size_t ws_size,
                              hipStream_t stream) {
    const float* x  = (const float*)d_in[0];
    const float* Wq = (const float*)d_in[1];
    const float* Wk = (const float*)d_in[2];
    const float* Wv = (const float*)d_in[3];
    float* out = (float*)d_out;

    char* ws = (char*)d_ws;
    short* Wt    = (short*)(ws);                          // 393216 B
    short* Q     = (short*)(ws + 393216);                 // 2097152 B
    short* K     = (short*)(ws + 2490368);                // 2097152 B
    short* Vt    = (short*)(ws + 4587520);                // 2097152 B
    short* Opart = (short*)(ws + 6684672);                // 576*128*64*2 = 9437184 B
    float* Mpart = (float*)(ws + 16121856);               // 294912 B
    float* Lpart = (float*)(ws + 16416768);               // 294912 B
    // total: 16711680 B (~16 MiB)

    hipLaunchKernelGGL(prep_w,   dim3(192),   dim3(256), 0, stream, Wq, Wk, Wv, Wt);
    hipLaunchKernelGGL(proj_qkv, dim3(512),   dim3(512), 0, stream, x, Wt, Q, K, Vt);
    hipLaunchKernelGGL(attn,     dim3(NTASK), dim3(512), 0, stream, Q, K, Vt,
                       Opart, Mpart, Lpart);
    hipLaunchKernelGGL(combine,  dim3(128),   dim3(256), 0, stream,
                       Opart, Mpart, Lpart, out);
}

// Round 7
// 68.341 us; speedup vs baseline: 1.9099x; 1.9099x over previous
//
#include <hip/hip_runtime.h>
#include <hip/hip_bf16.h>

// ---------- types ----------
typedef __attribute__((ext_vector_type(8))) short bf16x8;   // 8 bf16 in 4 VGPRs
typedef __attribute__((ext_vector_type(4))) short bf16x4;   // 4 bf16 in 2 VGPRs
typedef __attribute__((ext_vector_type(4))) float f32x4;
typedef __attribute__((ext_vector_type(4))) int   i32x4;

#define C2LOG 0.18033688011112042f   // 0.125 * log2(e): folds 1/sqrt(64) + base-2

// fp32 -> bf16 round-to-nearest-even
__device__ __forceinline__ short f2bf(float f) {
    union { float f; unsigned u; } v; v.f = f;
    unsigned r = v.u + 0x7fff + ((v.u >> 16) & 1);
    return (short)(r >> 16);
}
__device__ __forceinline__ unsigned packbf(float a, float b) {
    return (unsigned)(unsigned short)f2bf(a) | ((unsigned)(unsigned short)f2bf(b) << 16);
}
__device__ __forceinline__ float bf2f(short s) {
    union { unsigned u; float f; } v; v.u = ((unsigned)(unsigned short)s) << 16;
    return v.f;
}

// ---------- sizes ----------
#define BB 4
#define TT 4096
#define CC 1024
#define HD 64
#define NTASK_PB 144          // tasks per batch: sum_{g=0}^{7} 4*(g+1) = 144
#define NTASK (BB * NTASK_PB) // 576

// =====================================================================
// Kernel 1: pack W q/k/v (fp32 [1024][64]) -> transposed bf16 Wt[192][1024]
// =====================================================================
__global__ void prep_w(const float* __restrict__ Wq, const float* __restrict__ Wk,
                       const float* __restrict__ Wv, short* __restrict__ Wt) {
    const int n = blockIdx.x;                 // 0..191
    const float* W = (n < 64) ? Wq : (n < 128) ? Wk : Wv;
    const int col = n & 63;
    for (int k = threadIdx.x; k < CC; k += blockDim.x)
        Wt[n * CC + k] = f2bf(W[k * HD + col]);
}

// =====================================================================
// Kernel 2: QKV projection, double-buffered pipeline.
// Block = 32 x-rows, 8 waves; per kc-iter (K-chunk 64):
//   issue next x float4 (regs) + next W chunk (global_load_lds DMA,
//   pre-swizzled source, linear dest), compute 6 MFMA on current bufs,
//   convert+ds_write next x, vmcnt(0) + ONE barrier.
// x-staging: thread (tid>>4, tid&15) loads ONE float4 (cols q4*4..+3 of
// the 64-col chunk) -- max col 960+63 = 1023, in-bounds.
// Wave wv: m-half (wv&1), n-chunks (wv>>1)*3..+3.
// =====================================================================
__global__ __launch_bounds__(512) void proj_qkv(const float* __restrict__ x,
        const short* __restrict__ Wt, short* __restrict__ Q,
        short* __restrict__ K, short* __restrict__ Vt) {
    __shared__ short xs[2][32 * 72];      // x tile bf16, pad-72 (reg-staged)
    __shared__ short wsm[2][192 * 64];    // W chunk bf16, 128B rows, XOR-swizzled

    const int tid  = threadIdx.x;
    const int lane = tid & 63;
    const int wv   = tid >> 6;
    const int lm   = lane & 15;
    const int lg   = lane >> 4;
    const int mhalf = wv & 1;
    const int ngrp  = wv >> 1;
    const int mbase = blockIdx.x * 32;

    // x staging: thread (xr, xq4) loads one float4 of the 64-col chunk
    const int xr  = tid >> 4;             // 0..31
    const int xq4 = tid & 15;             // float4 index within chunk
    const float* xrow = x + (size_t)(mbase + xr) * CC;

    // W staging via DMA: 3 issues x 16B/lane; linear LDS dest, swizzled source
    int wsrow[3], wscol[3];
    #pragma unroll
    for (int it = 0; it < 3; ++it) {
        const int off = it * 8192 + wv * 1024 + lane * 16;     // byte off in tile
        wsrow[it] = off >> 7;                                  // W row 0..191
        wscol[it] = (off & 127) ^ ((wsrow[it] & 7) << 4);      // pre-swizzled byte col
    }

#define STAGE_W(bufidx, kc)                                                           \
    {                                                                                 \
        _Pragma("unroll")                                                             \
        for (int it = 0; it < 3; ++it) {                                              \
            const char* src = (const char*)(Wt + (size_t)wsrow[it] * CC + (kc) * 64)  \
                              + wscol[it];                                            \
            char* dst = (char*)&wsm[bufidx][0] + it * 8192 + wv * 1024;               \
            __builtin_amdgcn_global_load_lds(                                         \
                (const __attribute__((address_space(1))) unsigned*)src,               \
                (__attribute__((address_space(3))) unsigned*)dst, 16, 0, 0);          \
        }                                                                             \
    }

#define CONV_X(bufidx, xv)                                                            \
    {                                                                                 \
        bf16x4 bv;                                                                    \
        bv[0] = f2bf((xv).x); bv[1] = f2bf((xv).y);                                   \
        bv[2] = f2bf((xv).z); bv[3] = f2bf((xv).w);                                   \
        *reinterpret_cast<bf16x4*>(&xs[bufidx][xr * 72 + xq4 * 4]) = bv;              \
    }

    f32x4 acc[3];
    #pragma unroll
    for (int i = 0; i < 3; ++i) acc[i] = f32x4{0.f, 0.f, 0.f, 0.f};

    // ---- prologue: stage chunk 0 ----
    {
        float4 v = *reinterpret_cast<const float4*>(xrow + xq4 * 4);
        CONV_X(0, v)
        STAGE_W(0, 0)
    }
    asm volatile("s_waitcnt vmcnt(0)" ::: "memory");
    __syncthreads();

    const int arow = mhalf * 16 + lm;
    int buf = 0;
    for (int kc = 0; kc < 16; ++kc) {
        // ---- issue next tile (x -> regs, W -> DMA) ----
        float4 nv;
        const bool more = (kc < 15);
        if (more) {
            nv = *reinterpret_cast<const float4*>(xrow + (kc + 1) * 64 + xq4 * 4);
            STAGE_W(buf ^ 1, kc + 1)
        }

        // ---- compute on current buffers ----
        bf16x8 a0 = *reinterpret_cast<const bf16x8*>(&xs[buf][arow * 72 + lg * 8]);
        bf16x8 a1 = *reinterpret_cast<const bf16x8*>(&xs[buf][arow * 72 + 32 + lg * 8]);
        #pragma unroll
        for (int c = 0; c < 3; ++c) {
            const int brow = (ngrp * 3 + c) * 16 + lm;
            const int sw = (brow & 7) << 4;
            bf16x8 b0 = *reinterpret_cast<const bf16x8*>(
                (const char*)&wsm[buf][0] + brow * 128 + ((lg * 16) ^ sw));
            bf16x8 b1 = *reinterpret_cast<const bf16x8*>(
                (const char*)&wsm[buf][0] + brow * 128 + ((64 + lg * 16) ^ sw));
            acc[c] = __builtin_amdgcn_mfma_f32_16x16x32_bf16(a0, b0, acc[c], 0, 0, 0);
            acc[c] = __builtin_amdgcn_mfma_f32_16x16x32_bf16(a1, b1, acc[c], 0, 0, 0);
        }

        // ---- write next x tile, drain DMA, barrier ----
        if (more) CONV_X(buf ^ 1, nv)
        asm volatile("s_waitcnt vmcnt(0)" ::: "memory");
        __syncthreads();
        buf ^= 1;
    }
#undef STAGE_W
#undef CONV_X

    // ---- store: D row = mhalf*16 + lg*4 + r, col = cn*16 + lm ----
    const int mrow = mbase + mhalf * 16 + lg * 4;
    #pragma unroll
    for (int c = 0; c < 3; ++c) {
        const int cn = ngrp * 3 + c;
        if (cn < 4) {
            #pragma unroll
            for (int r = 0; r < 4; ++r)
                Q[(size_t)(mrow + r) * HD + cn * 16 + lm] = f2bf(acc[c][r]);
        } else if (cn < 8) {
            #pragma unroll
            for (int r = 0; r < 4; ++r)
                K[(size_t)(mrow + r) * HD + (cn - 4) * 16 + lm] = f2bf(acc[c][r]);
        } else {
            const int bb   = mbase >> 12;
            const int tloc = (mbase & 4095) + mhalf * 16 + lg * 4;
            bf16x4 v4;
            #pragma unroll
            for (int r = 0; r < 4; ++r) v4[r] = f2bf(acc[c][r]);
            *reinterpret_cast<bf16x4*>(
                Vt + (size_t)bb * (HD * TT) + (size_t)((cn - 8) * 16 + lm) * TT + tloc) = v4;
        }
    }
}

// =====================================================================
// Kernel 3: causal flash attention (unchanged from R4). Block = 128 q-rows
// (8 waves x 16), one KV segment; KV-64 tiles double-buffered in LDS via
// global_load_lds with XOR swizzle, shared by all 8 waves.
// =====================================================================
__global__ __launch_bounds__(512, 4) void attn(const short* __restrict__ Q,
        const short* __restrict__ K, const short* __restrict__ Vt,
        short* __restrict__ Opart, float* __restrict__ Mpart,
        float* __restrict__ Lpart) {
    __shared__ short ks[2][64 * 64];   // [buf][row=kv][d]  8KB each, swizzled
    __shared__ short vs[2][64 * 64];   // [buf][row=d][kv]  8KB each, swizzled

    const int tid  = threadIdx.x;
    const int lane = tid & 63;
    const int wv   = tid >> 6;
    const int lm   = lane & 15;
    const int lg   = lane >> 4;

    // ---- task decode: blockIdx.x = b*144 + t ----
    const int task = blockIdx.x;
    const int b  = task / NTASK_PB;
    int t_in = task - b * NTASK_PB;
    int g = 0;
    while (t_in >= 2 * (g + 1) * (g + 2)) ++g;          // g = i>>2, <=7
    const int idx = t_in - 2 * g * (g + 1);
    const int i   = 4 * g + idx / (g + 1);              // q-block 0..31
    const int seg = idx % (g + 1);                      // segment 0..g
    const int S   = g + 1;                              // segments for this i
    const int niter = 2 * i + 2;                        // KV-64 tiles in prefix
    const int qbase = i * 128;

    const size_t qkb = (size_t)b * TT * HD;
    const size_t vtb = (size_t)b * HD * TT;
    const int qrow = qbase + wv * 16;                   // wave's first q-row
    const int tmax = (qrow + 15) >> 6;                  // last useful tile

    // Q fragments (B-operand): lane holds Q[qrow+lm][lg*8+j]
    bf16x8 qf0 = *reinterpret_cast<const bf16x8*>(Q + qkb + (size_t)(qrow + lm) * HD + lg * 8);
    bf16x8 qf1 = *reinterpret_cast<const bf16x8*>(Q + qkb + (size_t)(qrow + lm) * HD + 32 + lg * 8);

    f32x4 o[4];
    #pragma unroll
    for (int c = 0; c < 4; ++c) o[c] = f32x4{0.f, 0.f, 0.f, 0.f};
    float mrun = -1e30f, lrun = 0.f;   // per-lane (q=lm), log2 domain

    const int srcA = lm + ((lane & 16) << 1);
    const int srcB = srcA + 16;
    const bool hihalf = (lane & 32) != 0;

    // staging geometry (per wave: 1KB chunk of each 8KB tile)
    const int lds_off = (wv << 10) + (lane << 4);       // byte offset in tile
    const int srow    = lds_off >> 7;                   // row this lane fills
    const int scolb   = (lds_off & 127) ^ ((srow & 7) << 4);  // pre-swizzled src col

#define STAGE_KV(bufidx, tt)                                                          \
    {                                                                                 \
        const char* ksrc = (const char*)(K + qkb) + (tt) * 8192 + (srow << 7) + scolb;\
        char* kdst = (char*)&ks[bufidx][0] + (wv << 10);                              \
        __builtin_amdgcn_global_load_lds(                                             \
            (const __attribute__((address_space(1))) unsigned*)ksrc,                  \
            (__attribute__((address_space(3))) unsigned*)kdst, 16, 0, 0);             \
        const char* vsrc = (const char*)(Vt + vtb) + (size_t)srow * (TT * 2)          \
                           + (tt) * 128 + scolb;                                      \
        char* vdst = (char*)&vs[bufidx][0] + (wv << 10);                              \
        __builtin_amdgcn_global_load_lds(                                             \
            (const __attribute__((address_space(1))) unsigned*)vsrc,                  \
            (__attribute__((address_space(3))) unsigned*)vdst, 16, 0, 0);             \
    }

    // prologue: stage first tile
    STAGE_KV(0, seg)
    asm volatile("s_waitcnt vmcnt(0)" ::: "memory");
    __syncthreads();

    int buf = 0;
    for (int t = seg; t < niter; t += S) {
        const int tn = t + S;
        if (tn < niter) STAGE_KV(buf ^ 1, tn)

        if (t <= tmax) {
            const short* ksb = &ks[buf][0];
            const short* vsb = &vs[buf][0];
            const int kv = t * 64;

            // ---- QK^T swapped: st[kt][r] = S[qrow+lm][kv + kt*16 + lg*4 + r] ----
            f32x4 st[4];
            #pragma unroll
            for (int kt = 0; kt < 4; ++kt) {
                const int krow = kt * 16 + lm;
                const int sw = (krow & 7) << 4;
                bf16x8 k0 = *reinterpret_cast<const bf16x8*>(
                    (const char*)ksb + krow * 128 + ((lg * 16) ^ sw));
                bf16x8 k1 = *reinterpret_cast<const bf16x8*>(
                    (const char*)ksb + krow * 128 + ((64 + lg * 16) ^ sw));
                f32x4 a = f32x4{0.f, 0.f, 0.f, 0.f};
                a = __builtin_amdgcn_mfma_f32_16x16x32_bf16(k0, qf0, a, 0, 0, 0);
                a = __builtin_amdgcn_mfma_f32_16x16x32_bf16(k1, qf1, a, 0, 0, 0);
                st[kt] = a;
            }
            // ---- to log2 domain + causal mask ----
            float s2[4][4];
            #pragma unroll
            for (int kt = 0; kt < 4; ++kt)
                #pragma unroll
                for (int r = 0; r < 4; ++r) s2[kt][r] = st[kt][r] * C2LOG;
            if (kv + 63 > qrow) {
                const int qg = qrow + lm;
                #pragma unroll
                for (int kt = 0; kt < 4; ++kt)
                    #pragma unroll
                    for (int r = 0; r < 4; ++r)
                        if (kv + kt * 16 + lg * 4 + r > qg) s2[kt][r] = -1e30f;
            }
            // ---- online softmax (q lane-local; 2 shfl per reduce) ----
            float mloc = s2[0][0];
            #pragma unroll
            for (int kt = 0; kt < 4; ++kt)
                #pragma unroll
                for (int r = 0; r < 4; ++r) mloc = fmaxf(mloc, s2[kt][r]);
            mloc = fmaxf(mloc, __shfl_xor(mloc, 16));
            mloc = fmaxf(mloc, __shfl_xor(mloc, 32));
            const float mnew = fmaxf(mrun, mloc);
            const float alpha = __builtin_amdgcn_exp2f(mrun - mnew);
            mrun = mnew;

            float p[4][4];
            float rs = 0.f;
            #pragma unroll
            for (int kt = 0; kt < 4; ++kt)
                #pragma unroll
                for (int r = 0; r < 4; ++r) {
                    p[kt][r] = __builtin_amdgcn_exp2f(s2[kt][r] - mnew);
                    rs += p[kt][r];
                }
            rs += __shfl_xor(rs, 16);
            rs += __shfl_xor(rs, 32);
            lrun = lrun * alpha + rs;

            // ---- pack P^T to bf16 pairs ----
            unsigned u[4][2];
            #pragma unroll
            for (int kt = 0; kt < 4; ++kt) {
                u[kt][0] = packbf(p[kt][0], p[kt][1]);
                u[kt][1] = packbf(p[kt][2], p[kt][3]);
            }
            // ---- rescale O^T ----
            #pragma unroll
            for (int c = 0; c < 4; ++c)
                #pragma unroll
                for (int r = 0; r < 4; ++r) o[c][r] *= alpha;

            // ---- PV: O^T += V^T . P ; B-frag via register redistribution ----
            #pragma unroll
            for (int h = 0; h < 2; ++h) {
                const int b0 = __shfl((int)u[2 * h][0], srcA);
                const int c0 = __shfl((int)u[2 * h + 1][0], srcA);
                const int b1 = __shfl((int)u[2 * h][1], srcA);
                const int c1 = __shfl((int)u[2 * h + 1][1], srcA);
                const int b2 = __shfl((int)u[2 * h][0], srcB);
                const int c2 = __shfl((int)u[2 * h + 1][0], srcB);
                const int b3 = __shfl((int)u[2 * h][1], srcB);
                const int c3 = __shfl((int)u[2 * h + 1][1], srcB);
                union { i32x4 iv; bf16x8 v; } cv;
                cv.iv = i32x4{ hihalf ? c0 : b0, hihalf ? c1 : b1,
                               hihalf ? c2 : b2, hihalf ? c3 : b3 };
                #pragma unroll
                for (int c = 0; c < 4; ++c) {
                    const int vrow = c * 16 + lm;
                    const int sw = (vrow & 7) << 4;
                    bf16x8 va = *reinterpret_cast<const bf16x8*>(
                        (const char*)vsb + vrow * 128 + ((h * 64 + lg * 16) ^ sw));
                    o[c] = __builtin_amdgcn_mfma_f32_16x16x32_bf16(va, cv.v, o[c], 0, 0, 0);
                }
            }
        }

        asm volatile("s_waitcnt vmcnt(0)" ::: "memory");
        __syncthreads();
        buf ^= 1;
    }
#undef STAGE_KV

    // ---- write partials: O bf16 (task,row,d), m/l fp32 ----
    short* Ob = Opart + (size_t)task * (128 * HD);
    #pragma unroll
    for (int c = 0; c < 4; ++c) {
        bf16x4 ov;
        #pragma unroll
        for (int r = 0; r < 4; ++r) ov[r] = f2bf(o[c][r]);
        *reinterpret_cast<bf16x4*>(&Ob[(wv * 16 + lm) * HD + c * 16 + lg * 4]) = ov;
    }
    if (lg == 0) {
        Mpart[task * 128 + wv * 16 + lm] = mrun;
        Lpart[task * 128 + wv * 16 + lm] = lrun;
    }
}

// =====================================================================
// Kernel 4: combine partials -> fp32 out. Block = (b, q-block i, row-grp).
// 1024 blocks (4/CU) x 256 threads; each thread one (row, 4 cols).
// =====================================================================
__global__ __launch_bounds__(256) void combine(const short* __restrict__ Opart,
        const float* __restrict__ Mpart, const float* __restrict__ Lpart,
        float* __restrict__ out) {
    const int b   = blockIdx.x >> 8;
    const int rem = blockIdx.x & 255;
    const int i   = rem >> 3;
    const int rr  = rem & 7;
    const int g = i >> 2;
    const int S = g + 1;
    const int task0 = b * NTASK_PB + 2 * g * (g + 1) + (i - 4 * g) * (g + 1);
    const int qbase = i * 128;

    const int tid = threadIdx.x;
    const int row = rr * 16 + (tid >> 4);   // 0..127
    const int cb  = (tid & 15) << 2;        // col (x4 floats)

    float mmax = -1e30f;
    float ms[8];
    for (int s = 0; s < S; ++s) {
        ms[s] = Mpart[(task0 + s) * 128 + row];
        mmax = fmaxf(mmax, ms[s]);
    }
    float lsum = 0.f;
    float a0 = 0.f, a1 = 0.f, a2 = 0.f, a3 = 0.f;
    for (int s = 0; s < S; ++s) {
        const float w = __builtin_amdgcn_exp2f(ms[s] - mmax);
        lsum += Lpart[(task0 + s) * 128 + row] * w;
        bf16x4 ov = *reinterpret_cast<const bf16x4*>(
            &Opart[((size_t)(task0 + s) * 128 + row) * HD + cb]);
        a0 += bf2f(ov[0]) * w;
        a1 += bf2f(ov[1]) * w;
        a2 += bf2f(ov[2]) * w;
        a3 += bf2f(ov[3]) * w;
    }
    const float inv = 1.0f / lsum;
    f32x4 res{ a0 * inv, a1 * inv, a2 * inv, a3 * inv };
    *reinterpret_cast<f32x4*>(
        &out[((size_t)b * TT + qbase + row) * HD + cb]) = res;
}

// =====================================================================
extern "C" void kernel_launch(void* const* d_in, const int* in_sizes, int n_in,
                              void* d_out, int out_size, void* d_ws, size_t ws_size,
                              hipStream_t stream) {
    const float* x  = (const float*)d_in[0];
    const float* Wq = (const float*)d_in[1];
    const float* Wk = (const float*)d_in[2];
    const float* Wv = (const float*)d_in[3];
    float* out = (float*)d_out;

    char* ws = (char*)d_ws;
    short* Wt    = (short*)(ws);                          // 393216 B
    short* Q     = (short*)(ws + 393216);                 // 2097152 B
    short* K     = (short*)(ws + 2490368);                // 2097152 B
    short* Vt    = (short*)(ws + 4587520);                // 2097152 B
    short* Opart = (short*)(ws + 6684672);                // 576*128*64*2 = 9437184 B
    float* Mpart = (float*)(ws + 16121856);               // 294912 B
    float* Lpart = (float*)(ws + 16416768);               // 294912 B
    // total: 16711680 B (~16 MiB)

    hipLaunchKernelGGL(prep_w,   dim3(192),   dim3(256), 0, stream, Wq, Wk, Wv, Wt);
    hipLaunchKernelGGL(proj_qkv, dim3(512),   dim3(512), 0, stream, x, Wt, Q, K, Vt);
    hipLaunchKernelGGL(attn,     dim3(NTASK), dim3(512), 0, stream, Q, K, Vt,
                       Opart, Mpart, Lpart);
    hipLaunchKernelGGL(combine,  dim3(1024),  dim3(256), 0, stream,
                       Opart, Mpart, Lpart, out);
}